// Round 1
// baseline (913.439 us; speedup 1.0000x reference)
//
#include <hip/hip_runtime.h>
#include <math.h>

#define BB 4
#define SS 1024
#define DD 1024
#define HH 16
#define DKK 64
#define NN (BB*SS)          // 4096 rows
#define LN_EPS 1e-5f

// ---------------------------------------------------------------------------
// K1: projection GEMM: out(B,H,S,dk) = X(N,D) @ W(D,D)^T + bias
// tiles 64x64, BK=16, 256 threads, 4x4 micro-tile per thread, f32.
// ---------------------------------------------------------------------------
__global__ __launch_bounds__(256)
void k_proj(const float* __restrict__ X, const float* __restrict__ W,
            const float* __restrict__ bias, float* __restrict__ out)
{
    __shared__ float As[16][68];
    __shared__ float Bs[16][68];
    const int row0 = blockIdx.x * 64;
    const int col0 = blockIdx.y * 64;
    const int t  = threadIdx.x;
    const int tm = t >> 4, tn = t & 15;
    const int lr = t >> 2;            // 0..63 tile row for staging
    const int lk = (t & 3) << 2;      // 0,4,8,12 k-offset for staging
    float c[4][4] = {};

    for (int kt = 0; kt < DD; kt += 16) {
        float4 av = *reinterpret_cast<const float4*>(&X[(size_t)(row0 + lr)*DD + kt + lk]);
        float4 bv = *reinterpret_cast<const float4*>(&W[(size_t)(col0 + lr)*DD + kt + lk]);
        As[lk+0][lr]=av.x; As[lk+1][lr]=av.y; As[lk+2][lr]=av.z; As[lk+3][lr]=av.w;
        Bs[lk+0][lr]=bv.x; Bs[lk+1][lr]=bv.y; Bs[lk+2][lr]=bv.z; Bs[lk+3][lr]=bv.w;
        __syncthreads();
        #pragma unroll
        for (int kk = 0; kk < 16; ++kk) {
            float4 a4 = *reinterpret_cast<const float4*>(&As[kk][tm<<2]);
            float4 b4 = *reinterpret_cast<const float4*>(&Bs[kk][tn<<2]);
            const float a[4] = {a4.x,a4.y,a4.z,a4.w};
            const float b[4] = {b4.x,b4.y,b4.z,b4.w};
            #pragma unroll
            for (int i = 0; i < 4; ++i)
                #pragma unroll
                for (int j = 0; j < 4; ++j)
                    c[i][j] += a[i]*b[j];
        }
        __syncthreads();
    }

    // out layout (B,H,S,dk): row n=b*S+s ; col = h*64+k ; col0 is 64-aligned
    const int h = col0 >> 6;
    #pragma unroll
    for (int i = 0; i < 4; ++i) {
        const int row = row0 + (tm<<2) + i;
        const int bb  = row >> 10;
        const int s   = row & 1023;
        const int k0  = tn << 2;
        float4 w;
        w.x = c[i][0] + bias[col0 + k0 + 0];
        w.y = c[i][1] + bias[col0 + k0 + 1];
        w.z = c[i][2] + bias[col0 + k0 + 2];
        w.w = c[i][3] + bias[col0 + k0 + 3];
        *reinterpret_cast<float4*>(&out[(((size_t)bb*HH + h)*SS + s)*DKK + k0]) = w;
    }
}

// ---------------------------------------------------------------------------
// K2: raw scores -> attn area of d_out.  scores = Q K^T * alpha
// per block: 64q x 64j tile of one (b,h); K-dim = dk = 64 fully staged.
// ---------------------------------------------------------------------------
__global__ __launch_bounds__(256)
void k_scores(const float* __restrict__ Q, const float* __restrict__ K,
              const float* __restrict__ at, float* __restrict__ attn)
{
    __shared__ float Qs[64][68];
    __shared__ float Ks[64][68];
    const int bh = blockIdx.z;
    const int q0 = blockIdx.x * 64;
    const int j0 = blockIdx.y * 64;
    const float alpha = 0.125f / at[0];   // 1/sqrt(64)/(TEMP*adaptive)
    const float* Qb = Q + (size_t)bh * SS * DKK;
    const float* Kb = K + (size_t)bh * SS * DKK;
    const int t  = threadIdx.x;
    const int lr = t >> 2;                // 0..63
    const int lc = (t & 3) << 4;          // 0,16,32,48

    #pragma unroll
    for (int u = 0; u < 4; ++u) {
        *reinterpret_cast<float4*>(&Qs[lr][lc + 4*u]) =
            *reinterpret_cast<const float4*>(&Qb[(size_t)(q0 + lr)*DKK + lc + 4*u]);
        *reinterpret_cast<float4*>(&Ks[lr][lc + 4*u]) =
            *reinterpret_cast<const float4*>(&Kb[(size_t)(j0 + lr)*DKK + lc + 4*u]);
    }
    __syncthreads();

    const int tm = t >> 4, tn = t & 15;
    float c[4][4] = {};
    for (int k = 0; k < DKK; k += 4) {
        float4 a4[4], b4[4];
        #pragma unroll
        for (int i = 0; i < 4; ++i) a4[i] = *reinterpret_cast<const float4*>(&Qs[(tm<<2)+i][k]);
        #pragma unroll
        for (int j = 0; j < 4; ++j) b4[j] = *reinterpret_cast<const float4*>(&Ks[(tn<<2)+j][k]);
        #pragma unroll
        for (int i = 0; i < 4; ++i)
            #pragma unroll
            for (int j = 0; j < 4; ++j)
                c[i][j] += a4[i].x*b4[j].x + a4[i].y*b4[j].y + a4[i].z*b4[j].z + a4[i].w*b4[j].w;
    }

    #pragma unroll
    for (int i = 0; i < 4; ++i) {
        const size_t base = ((size_t)bh*SS + q0 + (tm<<2) + i)*SS + j0 + (tn<<2);
        float4 w = make_float4(c[i][0]*alpha, c[i][1]*alpha, c[i][2]*alpha, c[i][3]*alpha);
        *reinterpret_cast<float4*>(&attn[base]) = w;
    }
}

// ---------------------------------------------------------------------------
// K2b: per-row max and sum(exp(x-max)).  One wave per row (4 rows/block).
// ---------------------------------------------------------------------------
__global__ __launch_bounds__(256)
void k_rowstats(const float* __restrict__ attn, float* __restrict__ rmax,
                float* __restrict__ rsum)
{
    const int row  = blockIdx.x * 4 + (threadIdx.x >> 6);
    const int lane = threadIdx.x & 63;
    const float* p = attn + (size_t)row * SS;
    float x[16];
    #pragma unroll
    for (int w = 0; w < 4; ++w) {
        float4 v = *reinterpret_cast<const float4*>(&p[(w*64 + lane)*4]);
        x[w*4+0]=v.x; x[w*4+1]=v.y; x[w*4+2]=v.z; x[w*4+3]=v.w;
    }
    float m = x[0];
    #pragma unroll
    for (int i = 1; i < 16; ++i) m = fmaxf(m, x[i]);
    float s = 0.f;
    #pragma unroll
    for (int i = 0; i < 16; ++i) s += __expf(x[i] - m);
    #pragma unroll
    for (int off = 32; off > 0; off >>= 1) {
        float mo = __shfl_xor(m, off, 64);
        float so = __shfl_xor(s, off, 64);
        float mn = fmaxf(m, mo);
        s = s*__expf(m - mn) + so*__expf(mo - mn);
        m = mn;
    }
    if (lane == 0) { rmax[row] = m; rsum[row] = s; }
}

// ---------------------------------------------------------------------------
// K3: normalize attn in place + ctx = attn @ V, ctx stored (H,B,S,dk).
// per block: 64 q-rows x full dk=64 of one (b,h); loop j in steps of 16.
// ---------------------------------------------------------------------------
__global__ __launch_bounds__(256)
void k_pv(float* __restrict__ attn, const float* __restrict__ V,
          const float* __restrict__ rmax, const float* __restrict__ rsum,
          float* __restrict__ ctx)
{
    __shared__ float Ps[16][68];
    __shared__ float Vs[16][68];
    const int bh = blockIdx.y;
    const int b  = bh >> 4, h = bh & 15;
    const int q0 = blockIdx.x * 64;
    const int t  = threadIdx.x;
    const int lr  = t >> 2;           // q row this thread stages (0..63)
    const int lk4 = (t & 3) << 2;     // j offset within 16 (0,4,8,12)
    const int qrow = q0 + lr;
    const float rm = rmax[(size_t)bh*SS + qrow];
    const float rs = 1.0f / rsum[(size_t)bh*SS + qrow];
    float* arow = attn + ((size_t)bh*SS + qrow)*SS;
    const float* Vb = V + (size_t)bh*SS*DKK;
    const int tm = t >> 4, tn = t & 15;
    float c[4][4] = {};

    for (int j0 = 0; j0 < SS; j0 += 16) {
        float4 sv = *reinterpret_cast<const float4*>(&arow[j0 + lk4]);
        float4 pv;
        pv.x = __expf(sv.x - rm) * rs;
        pv.y = __expf(sv.y - rm) * rs;
        pv.z = __expf(sv.z - rm) * rs;
        pv.w = __expf(sv.w - rm) * rs;
        *reinterpret_cast<float4*>(&arow[j0 + lk4]) = pv;   // final attn out
        Ps[lk4+0][lr]=pv.x; Ps[lk4+1][lr]=pv.y; Ps[lk4+2][lr]=pv.z; Ps[lk4+3][lr]=pv.w;
        // V tile: rows j0..j0+15 x 64 cols
        *reinterpret_cast<float4*>(&Vs[t>>4][(t&15)<<2]) =
            *reinterpret_cast<const float4*>(&Vb[(size_t)(j0 + (t>>4))*DKK + ((t&15)<<2)]);
        __syncthreads();
        #pragma unroll
        for (int kk = 0; kk < 16; ++kk) {
            float4 a4 = *reinterpret_cast<const float4*>(&Ps[kk][tm<<2]);
            float4 b4 = *reinterpret_cast<const float4*>(&Vs[kk][tn<<2]);
            const float a[4] = {a4.x,a4.y,a4.z,a4.w};
            const float b[4] = {b4.x,b4.y,b4.z,b4.w};
            #pragma unroll
            for (int i = 0; i < 4; ++i)
                #pragma unroll
                for (int j = 0; j < 4; ++j)
                    c[i][j] += a[i]*b[j];
        }
        __syncthreads();
    }

    // ctx layout (H,B,S,dk)
    #pragma unroll
    for (int i = 0; i < 4; ++i) {
        const int s = q0 + (tm<<2) + i;
        float4 w = make_float4(c[i][0], c[i][1], c[i][2], c[i][3]);
        *reinterpret_cast<float4*>(&ctx[(((size_t)h*BB + b)*SS + s)*DKK + (tn<<2)]) = w;
    }
}

// ---------------------------------------------------------------------------
// K4: out-proj GEMM + bias + residual: y(N,D) = ctx(N,D) @ wo^T + bo + query
// ---------------------------------------------------------------------------
__global__ __launch_bounds__(256)
void k_out(const float* __restrict__ X, const float* __restrict__ W,
           const float* __restrict__ bias, const float* __restrict__ resid,
           float* __restrict__ y)
{
    __shared__ float As[16][68];
    __shared__ float Bs[16][68];
    const int row0 = blockIdx.x * 64;
    const int col0 = blockIdx.y * 64;
    const int t  = threadIdx.x;
    const int tm = t >> 4, tn = t & 15;
    const int lr = t >> 2;
    const int lk = (t & 3) << 2;
    float c[4][4] = {};

    for (int kt = 0; kt < DD; kt += 16) {
        float4 av = *reinterpret_cast<const float4*>(&X[(size_t)(row0 + lr)*DD + kt + lk]);
        float4 bv = *reinterpret_cast<const float4*>(&W[(size_t)(col0 + lr)*DD + kt + lk]);
        As[lk+0][lr]=av.x; As[lk+1][lr]=av.y; As[lk+2][lr]=av.z; As[lk+3][lr]=av.w;
        Bs[lk+0][lr]=bv.x; Bs[lk+1][lr]=bv.y; Bs[lk+2][lr]=bv.z; Bs[lk+3][lr]=bv.w;
        __syncthreads();
        #pragma unroll
        for (int kk = 0; kk < 16; ++kk) {
            float4 a4 = *reinterpret_cast<const float4*>(&As[kk][tm<<2]);
            float4 b4 = *reinterpret_cast<const float4*>(&Bs[kk][tn<<2]);
            const float a[4] = {a4.x,a4.y,a4.z,a4.w};
            const float b[4] = {b4.x,b4.y,b4.z,b4.w};
            #pragma unroll
            for (int i = 0; i < 4; ++i)
                #pragma unroll
                for (int j = 0; j < 4; ++j)
                    c[i][j] += a[i]*b[j];
        }
        __syncthreads();
    }

    #pragma unroll
    for (int i = 0; i < 4; ++i) {
        const int row = row0 + (tm<<2) + i;
        const int k0  = col0 + (tn<<2);
        float4 rq = *reinterpret_cast<const float4*>(&resid[(size_t)row*DD + k0]);
        float4 w;
        w.x = c[i][0] + bias[k0+0] + rq.x;
        w.y = c[i][1] + bias[k0+1] + rq.y;
        w.z = c[i][2] + bias[k0+2] + rq.z;
        w.w = c[i][3] + bias[k0+3] + rq.w;
        *reinterpret_cast<float4*>(&y[(size_t)row*DD + k0]) = w;
    }
}

// ---------------------------------------------------------------------------
// K5: LayerNorm over last dim (1024), one block per row.
// ---------------------------------------------------------------------------
__global__ __launch_bounds__(256)
void k_ln(const float* __restrict__ y, const float* __restrict__ g,
          const float* __restrict__ be, float* __restrict__ out)
{
    const int row = blockIdx.x;
    const int t = threadIdx.x;
    float4 v = *reinterpret_cast<const float4*>(&y[(size_t)row*DD + t*4]);
    float s  = v.x + v.y + v.z + v.w;
    float ss = v.x*v.x + v.y*v.y + v.z*v.z + v.w*v.w;
    #pragma unroll
    for (int off = 32; off > 0; off >>= 1) {
        s  += __shfl_xor(s,  off, 64);
        ss += __shfl_xor(ss, off, 64);
    }
    __shared__ float red[8];
    const int lane = t & 63, wid = t >> 6;
    if (lane == 0) { red[wid] = s; red[4+wid] = ss; }
    __syncthreads();
    const float S1 = red[0]+red[1]+red[2]+red[3];
    const float S2 = red[4]+red[5]+red[6]+red[7];
    const float mu  = S1 * (1.0f/DD);
    const float var = fmaxf(S2 * (1.0f/DD) - mu*mu, 0.0f);
    const float rstd = rsqrtf(var + LN_EPS);
    float4 gv = *reinterpret_cast<const float4*>(&g[t*4]);
    float4 bv = *reinterpret_cast<const float4*>(&be[t*4]);
    float4 o;
    o.x = (v.x - mu)*rstd*gv.x + bv.x;
    o.y = (v.y - mu)*rstd*gv.y + bv.y;
    o.z = (v.z - mu)*rstd*gv.z + bv.z;
    o.w = (v.w - mu)*rstd*gv.w + bv.w;
    *reinterpret_cast<float4*>(&out[(size_t)row*DD + t*4]) = o;
}

// ---------------------------------------------------------------------------
extern "C" void kernel_launch(void* const* d_in, const int* in_sizes, int n_in,
                              void* d_out, int out_size, void* d_ws, size_t ws_size,
                              hipStream_t stream) {
    const float* query = (const float*)d_in[0];
    const float* key   = (const float*)d_in[1];
    const float* value = (const float*)d_in[2];
    const float* wq = (const float*)d_in[3];
    const float* bq = (const float*)d_in[4];
    const float* wk = (const float*)d_in[5];
    const float* bk = (const float*)d_in[6];
    const float* wv = (const float*)d_in[7];
    const float* bv = (const float*)d_in[8];
    const float* wo = (const float*)d_in[9];
    const float* bo = (const float*)d_in[10];
    // d_in[11] temporal_bias: constant along softmax axis -> no-op, skipped
    const float* at = (const float*)d_in[12];
    const float* g  = (const float*)d_in[13];
    const float* be = (const float*)d_in[14];

    float* out_ln = (float*)d_out;
    float* attn   = (float*)d_out + (size_t)NN*DD;

    float* Qw   = (float*)d_ws;                    // 16 MB
    float* Kw   = Qw  + (size_t)NN*DD;             // 16 MB
    float* Vw   = Kw  + (size_t)NN*DD;             // 16 MB
    float* ctx  = Vw  + (size_t)NN*DD;             // 16 MB
    float* rmax = ctx + (size_t)NN*DD;             // 256 KB
    float* rsum = rmax + (size_t)BB*HH*SS;         // 256 KB
    float* y    = Qw;                              // reuse Q after K2

    k_proj<<<dim3(NN/64, DD/64), 256, 0, stream>>>(query, wq, bq, Qw);
    k_proj<<<dim3(NN/64, DD/64), 256, 0, stream>>>(key,   wk, bk, Kw);
    k_proj<<<dim3(NN/64, DD/64), 256, 0, stream>>>(value, wv, bv, Vw);
    k_scores<<<dim3(SS/64, SS/64, BB*HH), 256, 0, stream>>>(Qw, Kw, at, attn);
    k_rowstats<<<BB*HH*SS/4, 256, 0, stream>>>(attn, rmax, rsum);
    k_pv<<<dim3(SS/64, BB*HH), 256, 0, stream>>>(attn, Vw, rmax, rsum, ctx);
    k_out<<<dim3(NN/64, DD/64), 256, 0, stream>>>(ctx, wo, bo, query, y);
    k_ln<<<NN, 256, 0, stream>>>(y, g, be, out_ln);
}

// Round 2
// 556.185 us; speedup vs baseline: 1.6423x; 1.6423x over previous
//
#include <hip/hip_runtime.h>
#include <math.h>

#define BB 4
#define SS 1024
#define DD 1024
#define HH 16
#define DKK 64
#define NN (BB*SS)          // 4096 rows
#define LN_EPS 1e-5f

typedef __attribute__((ext_vector_type(8))) short bf16x8;
typedef __attribute__((ext_vector_type(4))) float f32x4;
typedef __attribute__((address_space(3))) unsigned int lds_u32;
typedef const __attribute__((address_space(1))) unsigned int glb_u32;

static __device__ __forceinline__ unsigned short f2bf(float x){
    unsigned int u = __float_as_uint(x);
    u += 0x7fff + ((u >> 16) & 1);     // round-to-nearest-even
    return (unsigned short)(u >> 16);
}

// ---------------------------------------------------------------------------
// f32 -> bf16 conversion, 8 elems/thread, vectorized.
// ---------------------------------------------------------------------------
__global__ __launch_bounds__(256)
void k_cvt(const float* __restrict__ in, unsigned short* __restrict__ out){
    const size_t i = ((size_t)blockIdx.x*256 + threadIdx.x)*8;
    float4 a = *reinterpret_cast<const float4*>(&in[i]);
    float4 b = *reinterpret_cast<const float4*>(&in[i+4]);
    int4 w;
    w.x = (int)((unsigned)f2bf(a.x) | ((unsigned)f2bf(a.y) << 16));
    w.y = (int)((unsigned)f2bf(a.z) | ((unsigned)f2bf(a.w) << 16));
    w.z = (int)((unsigned)f2bf(b.x) | ((unsigned)f2bf(b.y) << 16));
    w.w = (int)((unsigned)f2bf(b.z) | ((unsigned)f2bf(b.w) << 16));
    *reinterpret_cast<int4*>(&out[i]) = w;
}

// ---------------------------------------------------------------------------
// bf16 MFMA GEMM: out = X(N,1024) @ W(M,1024)^T + bias [+resid]
// 128x128 tile, 256 thr = 4 waves (2x2), BK=32, global_load_lds width-16.
// MODE 0: out scattered to (B,H,S,dk), +bias.
// MODE 1: out row-major (N,D), +bias +resid.
// ---------------------------------------------------------------------------
template<int MODE>
__global__ __launch_bounds__(256)
void k_gemm(const unsigned short* __restrict__ X, const unsigned short* __restrict__ W,
            const float* __restrict__ bias, const float* __restrict__ resid,
            float* __restrict__ out)
{
    __shared__ __align__(16) unsigned short Als[128*32];
    __shared__ __align__(16) unsigned short Bls[128*32];
    const int row0 = blockIdx.x * 128;
    const int col0 = blockIdx.y * 128;
    const int t = threadIdx.x;
    const int w = t >> 6, l = t & 63;
    const int wr = w >> 1, wc = w & 1;

    f32x4 acc[4][4];
    #pragma unroll
    for (int m=0;m<4;++m)
        #pragma unroll
        for (int n=0;n<4;++n) acc[m][n] = (f32x4){0.f,0.f,0.f,0.f};

    const int srow  = l >> 2;        // 0..15 row within 16-row staging chunk
    const int skoff = (l & 3) * 8;   // k offset in elems (0,8,16,24)

    for (int kt = 0; kt < DD; kt += 32) {
        // wave w stages A rows [w*32, w*32+32) and B rows likewise; 2 chunks of 16 rows
        #pragma unroll
        for (int i=0;i<2;++i) {
            const unsigned short* ga = X + (size_t)(row0 + w*32 + i*16 + srow)*DD + kt + skoff;
            const unsigned short* gb = W + (size_t)(col0 + w*32 + i*16 + srow)*DD + kt + skoff;
            __builtin_amdgcn_global_load_lds((glb_u32*)ga, (lds_u32*)&Als[(w*2+i)*512], 16, 0, 0);
            __builtin_amdgcn_global_load_lds((glb_u32*)gb, (lds_u32*)&Bls[(w*2+i)*512], 16, 0, 0);
        }
        __syncthreads();
        bf16x8 af[4], bfr[4];
        #pragma unroll
        for (int m=0;m<4;++m)
            af[m] = *reinterpret_cast<const bf16x8*>(&Als[(wr*64 + m*16 + (l&15))*32 + (l>>4)*8]);
        #pragma unroll
        for (int n=0;n<4;++n)
            bfr[n] = *reinterpret_cast<const bf16x8*>(&Bls[(wc*64 + n*16 + (l&15))*32 + (l>>4)*8]);
        #pragma unroll
        for (int m=0;m<4;++m)
            #pragma unroll
            for (int n=0;n<4;++n)
                acc[m][n] = __builtin_amdgcn_mfma_f32_16x16x32_bf16(af[m], bfr[n], acc[m][n], 0, 0, 0);
        __syncthreads();
    }

    // epilogue: C/D layout col=lane&15, row=(lane>>4)*4+reg  [m89 verified]
    #pragma unroll
    for (int m=0;m<4;++m){
        const int grow_base = row0 + wr*64 + m*16 + ((l>>4)<<2);
        #pragma unroll
        for (int n=0;n<4;++n){
            const int col = col0 + wc*64 + n*16 + (l&15);
            const float bc = bias[col];
            #pragma unroll
            for (int r=0;r<4;++r){
                const int row = grow_base + r;
                float v = acc[m][n][r] + bc;
                if (MODE == 0) {
                    const int b = row >> 10, s = row & 1023, h = col >> 6, k = col & 63;
                    out[(((size_t)b*HH + h)*SS + s)*DKK + k] = v;
                } else {
                    v += resid[(size_t)row*DD + col];
                    out[(size_t)row*DD + col] = v;
                }
            }
        }
    }
}

// ---------------------------------------------------------------------------
// K2: raw scores -> attn area of d_out.  scores = Q K^T * alpha   (f32)
// ---------------------------------------------------------------------------
__global__ __launch_bounds__(256)
void k_scores(const float* __restrict__ Q, const float* __restrict__ K,
              const float* __restrict__ at, float* __restrict__ attn)
{
    __shared__ float Qs[64][68];
    __shared__ float Ks[64][68];
    const int bh = blockIdx.z;
    const int q0 = blockIdx.x * 64;
    const int j0 = blockIdx.y * 64;
    const float alpha = 0.125f / at[0];
    const float* Qb = Q + (size_t)bh * SS * DKK;
    const float* Kb = K + (size_t)bh * SS * DKK;
    const int t  = threadIdx.x;
    const int lr = t >> 2;
    const int lc = (t & 3) << 4;

    #pragma unroll
    for (int u = 0; u < 4; ++u) {
        *reinterpret_cast<float4*>(&Qs[lr][lc + 4*u]) =
            *reinterpret_cast<const float4*>(&Qb[(size_t)(q0 + lr)*DKK + lc + 4*u]);
        *reinterpret_cast<float4*>(&Ks[lr][lc + 4*u]) =
            *reinterpret_cast<const float4*>(&Kb[(size_t)(j0 + lr)*DKK + lc + 4*u]);
    }
    __syncthreads();

    const int tm = t >> 4, tn = t & 15;
    float c[4][4] = {};
    for (int k = 0; k < DKK; k += 4) {
        float4 a4[4], b4[4];
        #pragma unroll
        for (int i = 0; i < 4; ++i) a4[i] = *reinterpret_cast<const float4*>(&Qs[(tm<<2)+i][k]);
        #pragma unroll
        for (int j = 0; j < 4; ++j) b4[j] = *reinterpret_cast<const float4*>(&Ks[(tn<<2)+j][k]);
        #pragma unroll
        for (int i = 0; i < 4; ++i)
            #pragma unroll
            for (int j = 0; j < 4; ++j)
                c[i][j] += a4[i].x*b4[j].x + a4[i].y*b4[j].y + a4[i].z*b4[j].z + a4[i].w*b4[j].w;
    }

    #pragma unroll
    for (int i = 0; i < 4; ++i) {
        const size_t base = ((size_t)bh*SS + q0 + (tm<<2) + i)*SS + j0 + (tn<<2);
        float4 w = make_float4(c[i][0]*alpha, c[i][1]*alpha, c[i][2]*alpha, c[i][3]*alpha);
        *reinterpret_cast<float4*>(&attn[base]) = w;
    }
}

// ---------------------------------------------------------------------------
// K2b: per-row max and sum(exp(x-max)).  One wave per row.
// ---------------------------------------------------------------------------
__global__ __launch_bounds__(256)
void k_rowstats(const float* __restrict__ attn, float* __restrict__ rmax,
                float* __restrict__ rsum)
{
    const int row  = blockIdx.x * 4 + (threadIdx.x >> 6);
    const int lane = threadIdx.x & 63;
    const float* p = attn + (size_t)row * SS;
    float x[16];
    #pragma unroll
    for (int w = 0; w < 4; ++w) {
        float4 v = *reinterpret_cast<const float4*>(&p[(w*64 + lane)*4]);
        x[w*4+0]=v.x; x[w*4+1]=v.y; x[w*4+2]=v.z; x[w*4+3]=v.w;
    }
    float m = x[0];
    #pragma unroll
    for (int i = 1; i < 16; ++i) m = fmaxf(m, x[i]);
    float s = 0.f;
    #pragma unroll
    for (int i = 0; i < 16; ++i) s += __expf(x[i] - m);
    #pragma unroll
    for (int off = 32; off > 0; off >>= 1) {
        float mo = __shfl_xor(m, off, 64);
        float so = __shfl_xor(s, off, 64);
        float mn = fmaxf(m, mo);
        s = s*__expf(m - mn) + so*__expf(mo - mn);
        m = mn;
    }
    if (lane == 0) { rmax[row] = m; rsum[row] = s; }
}

// ---------------------------------------------------------------------------
// K3: normalize attn in place + ctx = attn @ V, ctx stored (H,B,S,dk). (f32)
// ---------------------------------------------------------------------------
__global__ __launch_bounds__(256)
void k_pv(float* __restrict__ attn, const float* __restrict__ V,
          const float* __restrict__ rmax, const float* __restrict__ rsum,
          float* __restrict__ ctx)
{
    __shared__ float Ps[16][68];
    __shared__ float Vs[16][68];
    const int bh = blockIdx.y;
    const int b  = bh >> 4, h = bh & 15;
    const int q0 = blockIdx.x * 64;
    const int t  = threadIdx.x;
    const int lr  = t >> 2;
    const int lk4 = (t & 3) << 2;
    const int qrow = q0 + lr;
    const float rm = rmax[(size_t)bh*SS + qrow];
    const float rs = 1.0f / rsum[(size_t)bh*SS + qrow];
    float* arow = attn + ((size_t)bh*SS + qrow)*SS;
    const float* Vb = V + (size_t)bh*SS*DKK;
    const int tm = t >> 4, tn = t & 15;
    float c[4][4] = {};

    for (int j0 = 0; j0 < SS; j0 += 16) {
        float4 sv = *reinterpret_cast<const float4*>(&arow[j0 + lk4]);
        float4 pv;
        pv.x = __expf(sv.x - rm) * rs;
        pv.y = __expf(sv.y - rm) * rs;
        pv.z = __expf(sv.z - rm) * rs;
        pv.w = __expf(sv.w - rm) * rs;
        *reinterpret_cast<float4*>(&arow[j0 + lk4]) = pv;
        Ps[lk4+0][lr]=pv.x; Ps[lk4+1][lr]=pv.y; Ps[lk4+2][lr]=pv.z; Ps[lk4+3][lr]=pv.w;
        *reinterpret_cast<float4*>(&Vs[t>>4][(t&15)<<2]) =
            *reinterpret_cast<const float4*>(&Vb[(size_t)(j0 + (t>>4))*DKK + ((t&15)<<2)]);
        __syncthreads();
        #pragma unroll
        for (int kk = 0; kk < 16; ++kk) {
            float4 a4 = *reinterpret_cast<const float4*>(&Ps[kk][tm<<2]);
            float4 b4 = *reinterpret_cast<const float4*>(&Vs[kk][tn<<2]);
            const float a[4] = {a4.x,a4.y,a4.z,a4.w};
            const float bb2[4] = {b4.x,b4.y,b4.z,b4.w};
            #pragma unroll
            for (int i = 0; i < 4; ++i)
                #pragma unroll
                for (int j = 0; j < 4; ++j)
                    c[i][j] += a[i]*bb2[j];
        }
        __syncthreads();
    }

    #pragma unroll
    for (int i = 0; i < 4; ++i) {
        const int s = q0 + (tm<<2) + i;
        float4 w = make_float4(c[i][0], c[i][1], c[i][2], c[i][3]);
        *reinterpret_cast<float4*>(&ctx[(((size_t)h*BB + b)*SS + s)*DKK + (tn<<2)]) = w;
    }
}

// ---------------------------------------------------------------------------
// K5: LayerNorm over last dim (1024), one block per row.
// ---------------------------------------------------------------------------
__global__ __launch_bounds__(256)
void k_ln(const float* __restrict__ y, const float* __restrict__ g,
          const float* __restrict__ be, float* __restrict__ out)
{
    const int row = blockIdx.x;
    const int t = threadIdx.x;
    float4 v = *reinterpret_cast<const float4*>(&y[(size_t)row*DD + t*4]);
    float s  = v.x + v.y + v.z + v.w;
    float ss = v.x*v.x + v.y*v.y + v.z*v.z + v.w*v.w;
    #pragma unroll
    for (int off = 32; off > 0; off >>= 1) {
        s  += __shfl_xor(s,  off, 64);
        ss += __shfl_xor(ss, off, 64);
    }
    __shared__ float red[8];
    const int lane = t & 63, wid = t >> 6;
    if (lane == 0) { red[wid] = s; red[4+wid] = ss; }
    __syncthreads();
    const float S1 = red[0]+red[1]+red[2]+red[3];
    const float S2 = red[4]+red[5]+red[6]+red[7];
    const float mu  = S1 * (1.0f/DD);
    const float var = fmaxf(S2 * (1.0f/DD) - mu*mu, 0.0f);
    const float rstd = rsqrtf(var + LN_EPS);
    float4 gv = *reinterpret_cast<const float4*>(&g[t*4]);
    float4 bv = *reinterpret_cast<const float4*>(&be[t*4]);
    float4 o;
    o.x = (v.x - mu)*rstd*gv.x + bv.x;
    o.y = (v.y - mu)*rstd*gv.y + bv.y;
    o.z = (v.z - mu)*rstd*gv.z + bv.z;
    o.w = (v.w - mu)*rstd*gv.w + bv.w;
    *reinterpret_cast<float4*>(&out[(size_t)row*DD + t*4]) = o;
}

// ---------------------------------------------------------------------------
extern "C" void kernel_launch(void* const* d_in, const int* in_sizes, int n_in,
                              void* d_out, int out_size, void* d_ws, size_t ws_size,
                              hipStream_t stream) {
    const float* query = (const float*)d_in[0];
    const float* key   = (const float*)d_in[1];
    const float* value = (const float*)d_in[2];
    const float* wq = (const float*)d_in[3];
    const float* bq = (const float*)d_in[4];
    const float* wk = (const float*)d_in[5];
    const float* bk = (const float*)d_in[6];
    const float* wv = (const float*)d_in[7];
    const float* bv = (const float*)d_in[8];
    const float* wo = (const float*)d_in[9];
    const float* bo = (const float*)d_in[10];
    // d_in[11] temporal_bias: constant along softmax axis -> no-op
    const float* at = (const float*)d_in[12];
    const float* g  = (const float*)d_in[13];
    const float* be = (const float*)d_in[14];

    float* out_ln = (float*)d_out;
    float* attn   = (float*)d_out + (size_t)NN*DD;

    float* base = (float*)d_ws;
    float* Qw   = base;                             // [0, 16MB)   f32, later y
    float* Kw   = base + (size_t)4*1024*1024;       // [16, 32MB)  f32
    float* Vw   = base + (size_t)8*1024*1024;       // [32, 48MB)  f32
    float* ctx  = base + (size_t)12*1024*1024;      // [48, 64MB)  f32 (written by k_pv)
    float* rmax = base + (size_t)16*1024*1024;      // [64MB, +256KB)
    float* rsum = rmax + (size_t)BB*HH*SS;
    float* y    = Qw;

    // bf16 staging aliases (regions dead at time of use):
    unsigned short* xb   = (unsigned short*)ctx;                         // 8MB, dead before k_pv
    unsigned short* wb   = (unsigned short*)(base + (size_t)14*1024*1024); // 2MB, dead before k_pv
    unsigned short* ctxb = (unsigned short*)Kw;                          // Kw dead after k_scores
    unsigned short* wob  = (unsigned short*)Vw;                          // Vw dead after k_pv

    const dim3 ggrid(NN/128, DD/128);

    // Q projection
    k_cvt<<<2048, 256, 0, stream>>>(query, xb);
    k_cvt<<<512,  256, 0, stream>>>(wq, wb);
    k_gemm<0><<<ggrid, 256, 0, stream>>>(xb, wb, bq, nullptr, Qw);
    // K projection
    k_cvt<<<2048, 256, 0, stream>>>(key, xb);
    k_cvt<<<512,  256, 0, stream>>>(wk, wb);
    k_gemm<0><<<ggrid, 256, 0, stream>>>(xb, wb, bk, nullptr, Kw);
    // V projection
    k_cvt<<<2048, 256, 0, stream>>>(value, xb);
    k_cvt<<<512,  256, 0, stream>>>(wv, wb);
    k_gemm<0><<<ggrid, 256, 0, stream>>>(xb, wb, bv, nullptr, Vw);

    // attention (f32, unchanged this round)
    k_scores<<<dim3(SS/64, SS/64, BB*HH), 256, 0, stream>>>(Qw, Kw, at, attn);
    k_rowstats<<<BB*HH*SS/4, 256, 0, stream>>>(attn, rmax, rsum);
    k_pv<<<dim3(SS/64, BB*HH), 256, 0, stream>>>(attn, Vw, rmax, rsum, ctx);

    // out projection + residual, then LN
    k_cvt<<<2048, 256, 0, stream>>>(ctx, ctxb);
    k_cvt<<<512,  256, 0, stream>>>(wo, wob);
    k_gemm<1><<<ggrid, 256, 0, stream>>>(ctxb, wob, bo, query, y);
    k_ln<<<NN, 256, 0, stream>>>(y, g, be, out_ln);
}

// Round 3
// 259.127 us; speedup vs baseline: 3.5251x; 2.1464x over previous
//
#include <hip/hip_runtime.h>
#include <math.h>

#define BB 4
#define SS 1024
#define DD 1024
#define HH 16
#define DKK 64
#define NN (BB*SS)          // 4096 rows
#define LN_EPS 1e-5f
#define QB 64
#define JB 64

typedef __attribute__((ext_vector_type(8))) short bf16x8;
typedef __attribute__((ext_vector_type(4))) float f32x4;
typedef __attribute__((address_space(3))) unsigned int lds_u32;
typedef const __attribute__((address_space(1))) unsigned int glb_u32;

static __device__ __forceinline__ unsigned short f2bf(float x){
    unsigned int u = __float_as_uint(x);
    u += 0x7fff + ((u >> 16) & 1);     // round-to-nearest-even
    return (unsigned short)(u >> 16);
}

// ---------------------------------------------------------------------------
// f32 -> bf16 conversion, 8 elems/thread.
// ---------------------------------------------------------------------------
__global__ __launch_bounds__(256)
void k_cvt(const float* __restrict__ in, unsigned short* __restrict__ out){
    const size_t i = ((size_t)blockIdx.x*256 + threadIdx.x)*8;
    float4 a = *reinterpret_cast<const float4*>(&in[i]);
    float4 b = *reinterpret_cast<const float4*>(&in[i+4]);
    int4 w;
    w.x = (int)((unsigned)f2bf(a.x) | ((unsigned)f2bf(a.y) << 16));
    w.y = (int)((unsigned)f2bf(a.z) | ((unsigned)f2bf(a.w) << 16));
    w.z = (int)((unsigned)f2bf(b.x) | ((unsigned)f2bf(b.y) << 16));
    w.w = (int)((unsigned)f2bf(b.z) | ((unsigned)f2bf(b.w) << 16));
    *reinterpret_cast<int4*>(&out[i]) = w;
}

// ---------------------------------------------------------------------------
// bf16 MFMA GEMM: out = X(N,1024) @ W(M,1024)^T + bias [+resid]
// 128x128 tile, 256 thr = 4 waves (2x2), BK=32, global_load_lds width-16.
// MODE 0: bf16 out scattered to (B,H,S,dk).
// MODE 1: f32 out row-major (N,D), +resid.
// MODE 2: bf16 out transposed (B,H,dk,S)  [for V].
// ---------------------------------------------------------------------------
template<int MODE>
__global__ __launch_bounds__(256)
void k_gemm(const unsigned short* __restrict__ X, const unsigned short* __restrict__ W,
            const float* __restrict__ bias, const float* __restrict__ resid,
            float* __restrict__ outf, unsigned short* __restrict__ outb)
{
    __shared__ __align__(16) unsigned short Als[128*32];
    __shared__ __align__(16) unsigned short Bls[128*32];
    const int row0 = blockIdx.x * 128;
    const int col0 = blockIdx.y * 128;
    const int t = threadIdx.x;
    const int w = t >> 6, l = t & 63;
    const int wr = w >> 1, wc = w & 1;

    f32x4 acc[4][4];
    #pragma unroll
    for (int m=0;m<4;++m)
        #pragma unroll
        for (int n=0;n<4;++n) acc[m][n] = (f32x4){0.f,0.f,0.f,0.f};

    const int srow  = l >> 2;
    const int skoff = (l & 3) * 8;

    for (int kt = 0; kt < DD; kt += 32) {
        #pragma unroll
        for (int i=0;i<2;++i) {
            const unsigned short* ga = X + (size_t)(row0 + w*32 + i*16 + srow)*DD + kt + skoff;
            const unsigned short* gb = W + (size_t)(col0 + w*32 + i*16 + srow)*DD + kt + skoff;
            __builtin_amdgcn_global_load_lds((glb_u32*)ga, (lds_u32*)&Als[(w*2+i)*512], 16, 0, 0);
            __builtin_amdgcn_global_load_lds((glb_u32*)gb, (lds_u32*)&Bls[(w*2+i)*512], 16, 0, 0);
        }
        __syncthreads();
        bf16x8 af[4], bfr[4];
        #pragma unroll
        for (int m=0;m<4;++m)
            af[m] = *reinterpret_cast<const bf16x8*>(&Als[(wr*64 + m*16 + (l&15))*32 + (l>>4)*8]);
        #pragma unroll
        for (int n=0;n<4;++n)
            bfr[n] = *reinterpret_cast<const bf16x8*>(&Bls[(wc*64 + n*16 + (l&15))*32 + (l>>4)*8]);
        #pragma unroll
        for (int m=0;m<4;++m)
            #pragma unroll
            for (int n=0;n<4;++n)
                acc[m][n] = __builtin_amdgcn_mfma_f32_16x16x32_bf16(af[m], bfr[n], acc[m][n], 0, 0, 0);
        __syncthreads();
    }

    // C/D layout: col=lane&15, row=(lane>>4)*4+reg
    #pragma unroll
    for (int m=0;m<4;++m){
        const int grow_base = row0 + wr*64 + m*16 + ((l>>4)<<2);
        #pragma unroll
        for (int n=0;n<4;++n){
            const int col = col0 + wc*64 + n*16 + (l&15);
            const float bc = bias[col];
            if (MODE == 2) {
                const int b = grow_base >> 10, s = grow_base & 1023;
                const int h = col >> 6, k = col & 63;
                ushort4 pk;
                pk.x = f2bf(acc[m][n][0] + bc);
                pk.y = f2bf(acc[m][n][1] + bc);
                pk.z = f2bf(acc[m][n][2] + bc);
                pk.w = f2bf(acc[m][n][3] + bc);
                *reinterpret_cast<ushort4*>(&outb[(((size_t)b*HH + h)*DKK + k)*SS + s]) = pk;
            } else {
                #pragma unroll
                for (int r=0;r<4;++r){
                    const int row = grow_base + r;
                    float v = acc[m][n][r] + bc;
                    if (MODE == 0) {
                        const int b = row >> 10, s = row & 1023, h = col >> 6, k = col & 63;
                        outb[(((size_t)b*HH + h)*SS + s)*DKK + k] = f2bf(v);
                    } else {
                        v += resid[(size_t)row*DD + col];
                        outf[(size_t)row*DD + col] = v;
                    }
                }
            }
        }
    }
}

// ---------------------------------------------------------------------------
// Fused attention: per block = one 64-row q-tile of one (b,h).
// Pass 1: online row max/sum of exp over all j (MFMA QK^T, stats in regs).
// Pass 2: recompute QK^T, write normalized attn (f32, nontemporal), P->bf16
//         in LDS, PV MFMA accumulate, ctx written bf16 in (H,B,S,dk).
// LDS tiles XOR-swizzled to kill ds_read_b128 row-stride-128B conflicts.
// ---------------------------------------------------------------------------
__global__ __launch_bounds__(256)
void k_attn(const unsigned short* __restrict__ Qb, const unsigned short* __restrict__ Kb,
            const unsigned short* __restrict__ Vtb, const float* __restrict__ at,
            float* __restrict__ attn, unsigned short* __restrict__ ctxb)
{
    __shared__ __align__(16) unsigned short Qs[QB*64];
    __shared__ __align__(16) unsigned short Ks[JB*64];
    __shared__ __align__(16) unsigned short Vs[DKK*JB];   // V^T tile [d][j]
    __shared__ __align__(16) unsigned short Ps[QB*JB];
    const int bh = blockIdx.y;
    const int q0 = blockIdx.x * QB;
    const int t = threadIdx.x, w = t >> 6, l = t & 63;
    const float alpha = 0.125f / at[0];

    const unsigned short* Qg = Qb  + (size_t)bh*SS*DKK;
    const unsigned short* Kg = Kb  + (size_t)bh*SS*DKK;
    const unsigned short* Vg = Vtb + (size_t)bh*DKK*SS;

    // ---- stage Q tile (once), swizzled ----
    #pragma unroll
    for (int p = 0; p < 2; ++p) {
        const int c = t + p*256;
        const int q = c >> 3, kc = (c & 7) * 8;
        int4 v = *reinterpret_cast<const int4*>(&Qg[(size_t)(q0 + q)*DKK + kc]);
        *reinterpret_cast<int4*>((char*)Qs + ((q*128 + kc*2) ^ ((q & 7) << 4))) = v;
    }
    __syncthreads();
    bf16x8 qf[2];
    {
        const int q = w*16 + (l & 15);
        #pragma unroll
        for (int ks = 0; ks < 2; ++ks)
            qf[ks] = *reinterpret_cast<const bf16x8*>(
                (char*)Qs + ((q*128 + (l>>4)*16 + ks*64) ^ ((q & 7) << 4)));
    }

    float m[4], s[4];
    #pragma unroll
    for (int r = 0; r < 4; ++r) { m[r] = -1e30f; s[r] = 0.f; }

    // ================= pass 1: stats =================
    for (int j0 = 0; j0 < SS; j0 += JB) {
        #pragma unroll
        for (int p = 0; p < 2; ++p) {
            const int c = t + p*256;
            const int j = c >> 3, kc = (c & 7) * 8;
            int4 v = *reinterpret_cast<const int4*>(&Kg[(size_t)(j0 + j)*DKK + kc]);
            *reinterpret_cast<int4*>((char*)Ks + ((j*128 + kc*2) ^ ((j & 7) << 4))) = v;
        }
        __syncthreads();
        f32x4 acc[4];
        #pragma unroll
        for (int n = 0; n < 4; ++n) acc[n] = (f32x4){0.f,0.f,0.f,0.f};
        #pragma unroll
        for (int ks = 0; ks < 2; ++ks) {
            #pragma unroll
            for (int n = 0; n < 4; ++n) {
                const int j = n*16 + (l & 15);
                bf16x8 kf = *reinterpret_cast<const bf16x8*>(
                    (char*)Ks + ((j*128 + (l>>4)*16 + ks*64) ^ ((j & 7) << 4)));
                acc[n] = __builtin_amdgcn_mfma_f32_16x16x32_bf16(qf[ks], kf, acc[n], 0, 0, 0);
            }
        }
        #pragma unroll
        for (int r = 0; r < 4; ++r) {
            float tm = fmaxf(fmaxf(acc[0][r], acc[1][r]), fmaxf(acc[2][r], acc[3][r])) * alpha;
            #pragma unroll
            for (int off = 1; off < 16; off <<= 1)
                tm = fmaxf(tm, __shfl_xor(tm, off, 64));
            const float mn = fmaxf(m[r], tm);
            float ps = __expf(acc[0][r]*alpha - mn) + __expf(acc[1][r]*alpha - mn)
                     + __expf(acc[2][r]*alpha - mn) + __expf(acc[3][r]*alpha - mn);
            #pragma unroll
            for (int off = 1; off < 16; off <<= 1)
                ps += __shfl_xor(ps, off, 64);
            s[r] = s[r] * __expf(m[r] - mn) + ps;
            m[r] = mn;
        }
        __syncthreads();
    }

    float sinv[4];
    #pragma unroll
    for (int r = 0; r < 4; ++r) sinv[r] = 1.0f / s[r];

    // ================= pass 2: attn write + PV =================
    f32x4 cacc[4];
    #pragma unroll
    for (int n = 0; n < 4; ++n) cacc[n] = (f32x4){0.f,0.f,0.f,0.f};

    for (int j0 = 0; j0 < SS; j0 += JB) {
        #pragma unroll
        for (int p = 0; p < 2; ++p) {
            const int c = t + p*256;
            const int j = c >> 3, kc = (c & 7) * 8;
            int4 v = *reinterpret_cast<const int4*>(&Kg[(size_t)(j0 + j)*DKK + kc]);
            *reinterpret_cast<int4*>((char*)Ks + ((j*128 + kc*2) ^ ((j & 7) << 4))) = v;
            const int d = c >> 3, jc = (c & 7) * 8;
            int4 vv = *reinterpret_cast<const int4*>(&Vg[(size_t)d*SS + j0 + jc]);
            *reinterpret_cast<int4*>((char*)Vs + ((d*128 + jc*2) ^ ((d & 7) << 4))) = vv;
        }
        __syncthreads();
        f32x4 acc[4];
        #pragma unroll
        for (int n = 0; n < 4; ++n) acc[n] = (f32x4){0.f,0.f,0.f,0.f};
        #pragma unroll
        for (int ks = 0; ks < 2; ++ks) {
            #pragma unroll
            for (int n = 0; n < 4; ++n) {
                const int j = n*16 + (l & 15);
                bf16x8 kf = *reinterpret_cast<const bf16x8*>(
                    (char*)Ks + ((j*128 + (l>>4)*16 + ks*64) ^ ((j & 7) << 4)));
                acc[n] = __builtin_amdgcn_mfma_f32_16x16x32_bf16(qf[ks], kf, acc[n], 0, 0, 0);
            }
        }
        // normalized P: write attn (f32) + Ps (bf16, swizzled)
        #pragma unroll
        for (int n = 0; n < 4; ++n) {
            const int jl = n*16 + (l & 15);
            #pragma unroll
            for (int r = 0; r < 4; ++r) {
                const int q = w*16 + (l>>4)*4 + r;
                const float p = __expf(acc[n][r]*alpha - m[r]) * sinv[r];
                __builtin_nontemporal_store(p, &attn[((size_t)bh*SS + q0 + q)*SS + j0 + jl]);
                *reinterpret_cast<unsigned short*>(
                    (char*)Ps + ((q*128 + jl*2) ^ ((q & 7) << 4))) = f2bf(p);
            }
        }
        __syncthreads();
        // PV
        #pragma unroll
        for (int ks = 0; ks < 2; ++ks) {
            const int qr = w*16 + (l & 15);
            bf16x8 pf = *reinterpret_cast<const bf16x8*>(
                (char*)Ps + ((qr*128 + (l>>4)*16 + ks*64) ^ ((qr & 7) << 4)));
            #pragma unroll
            for (int n = 0; n < 4; ++n) {
                const int d = n*16 + (l & 15);
                bf16x8 vf = *reinterpret_cast<const bf16x8*>(
                    (char*)Vs + ((d*128 + (l>>4)*16 + ks*64) ^ ((d & 7) << 4)));
                cacc[n] = __builtin_amdgcn_mfma_f32_16x16x32_bf16(pf, vf, cacc[n], 0, 0, 0);
            }
        }
        __syncthreads();
    }

    // ctx store bf16, layout (H,B,S,dk)
    const int b = bh >> 4, h = bh & 15;
    #pragma unroll
    for (int n = 0; n < 4; ++n) {
        const int d = n*16 + (l & 15);
        #pragma unroll
        for (int r = 0; r < 4; ++r) {
            const int q = q0 + w*16 + (l>>4)*4 + r;
            ctxb[(((size_t)h*BB + b)*SS + q)*DKK + d] = f2bf(cacc[n][r]);
        }
    }
}

// ---------------------------------------------------------------------------
// LayerNorm over last dim (1024), one block per row.
// ---------------------------------------------------------------------------
__global__ __launch_bounds__(256)
void k_ln(const float* __restrict__ y, const float* __restrict__ g,
          const float* __restrict__ be, float* __restrict__ out)
{
    const int row = blockIdx.x;
    const int t = threadIdx.x;
    float4 v = *reinterpret_cast<const float4*>(&y[(size_t)row*DD + t*4]);
    float s  = v.x + v.y + v.z + v.w;
    float ss = v.x*v.x + v.y*v.y + v.z*v.z + v.w*v.w;
    #pragma unroll
    for (int off = 32; off > 0; off >>= 1) {
        s  += __shfl_xor(s,  off, 64);
        ss += __shfl_xor(ss, off, 64);
    }
    __shared__ float red[8];
    const int lane = t & 63, wid = t >> 6;
    if (lane == 0) { red[wid] = s; red[4+wid] = ss; }
    __syncthreads();
    const float S1 = red[0]+red[1]+red[2]+red[3];
    const float S2 = red[4]+red[5]+red[6]+red[7];
    const float mu  = S1 * (1.0f/DD);
    const float var = fmaxf(S2 * (1.0f/DD) - mu*mu, 0.0f);
    const float rstd = rsqrtf(var + LN_EPS);
    float4 gv = *reinterpret_cast<const float4*>(&g[t*4]);
    float4 bv = *reinterpret_cast<const float4*>(&be[t*4]);
    float4 o;
    o.x = (v.x - mu)*rstd*gv.x + bv.x;
    o.y = (v.y - mu)*rstd*gv.y + bv.y;
    o.z = (v.z - mu)*rstd*gv.z + bv.z;
    o.w = (v.w - mu)*rstd*gv.w + bv.w;
    *reinterpret_cast<float4*>(&out[(size_t)row*DD + t*4]) = o;
}

// ---------------------------------------------------------------------------
extern "C" void kernel_launch(void* const* d_in, const int* in_sizes, int n_in,
                              void* d_out, int out_size, void* d_ws, size_t ws_size,
                              hipStream_t stream) {
    const float* query = (const float*)d_in[0];
    const float* key   = (const float*)d_in[1];
    const float* value = (const float*)d_in[2];
    const float* wq = (const float*)d_in[3];
    const float* bq = (const float*)d_in[4];
    const float* wk = (const float*)d_in[5];
    const float* bk = (const float*)d_in[6];
    const float* wv = (const float*)d_in[7];
    const float* bv = (const float*)d_in[8];
    const float* wo = (const float*)d_in[9];
    const float* bo = (const float*)d_in[10];
    // d_in[11] temporal_bias: constant along softmax axis -> softmax-invariant
    const float* at = (const float*)d_in[12];
    const float* g  = (const float*)d_in[13];
    const float* be = (const float*)d_in[14];

    float* out_ln = (float*)d_out;
    float* attn   = (float*)d_out + (size_t)NN*DD;

    char* wsb = (char*)d_ws;
    unsigned short* Qb   = (unsigned short*)(wsb);                    // 8 MB (B,H,S,dk)
    unsigned short* Kb   = (unsigned short*)(wsb + ((size_t)8<<20));  // 8 MB (B,H,S,dk)
    unsigned short* Vtb  = (unsigned short*)(wsb + ((size_t)16<<20)); // 8 MB (B,H,dk,S)
    unsigned short* ctxb = (unsigned short*)(wsb + ((size_t)24<<20)); // 8 MB (H,B,S,dk)
    unsigned short* xb   = (unsigned short*)(wsb + ((size_t)32<<20)); // 8 MB
    unsigned short* wb   = (unsigned short*)(wsb + ((size_t)40<<20)); // 2 MB
    float*          y    = (float*)(wsb + ((size_t)42<<20));          // 16 MB

    const dim3 ggrid(NN/128, DD/128);

    k_cvt<<<2048, 256, 0, stream>>>(query, xb);
    k_cvt<<<512,  256, 0, stream>>>(wq, wb);
    k_gemm<0><<<ggrid, 256, 0, stream>>>(xb, wb, bq, nullptr, nullptr, Qb);

    k_cvt<<<2048, 256, 0, stream>>>(key, xb);
    k_cvt<<<512,  256, 0, stream>>>(wk, wb);
    k_gemm<0><<<ggrid, 256, 0, stream>>>(xb, wb, bk, nullptr, nullptr, Kb);

    k_cvt<<<2048, 256, 0, stream>>>(value, xb);
    k_cvt<<<512,  256, 0, stream>>>(wv, wb);
    k_gemm<2><<<ggrid, 256, 0, stream>>>(xb, wb, bv, nullptr, nullptr, Vtb);

    k_attn<<<dim3(SS/QB, BB*HH), 256, 0, stream>>>(Qb, Kb, Vtb, at, attn, ctxb);

    k_cvt<<<512,  256, 0, stream>>>(wo, wb);
    k_gemm<1><<<ggrid, 256, 0, stream>>>(ctxb, wb, bo, query, y, nullptr);

    k_ln<<<NN, 256, 0, stream>>>(y, g, be, out_ln);
}